// Round 9
// baseline (39.098 us; speedup 1.0000x reference)
//
#include <hip/hip_runtime.h>
#include <hip/hip_bf16.h>

#define NUM_HEADS 16
#define HEAD_DIM  64
#define HD        1024   // NUM_HEADS*HEAD_DIM
#define SEQL      1024
#define NTILE     16     // kv tiles per sequence
#define TILE_E    4096   // elements per 64x64 bf16 tile (8 KB)
#define HSTRIDE   (64 * TILE_E)          // 64 tiles per head
#define VT_OFF    (NUM_HEADS * HSTRIDE)  // V-fragment array offset in ws (elems)
#define FIXED_M   12.0f                  // fixed log2-domain shift (max score ~8 sigma)
#define QK_SCALE  0.1803368801111204f    // 0.125 * log2(e), folded into K during prep

typedef __bf16 bf16x8 __attribute__((ext_vector_type(8)));
typedef float  f32x4  __attribute__((ext_vector_type(4)));

#define MFMA16(A, B, C) __builtin_amdgcn_mfma_f32_16x16x32_bf16((A), (B), (C), 0, 0, 0)
#define GLOAD_LDS16(gp, lp) \
  __builtin_amdgcn_global_load_lds((const __attribute__((address_space(1))) void*)(gp), \
                                   (__attribute__((address_space(3))) void*)(lp), 16, 0, 0)

// ---------------- prep: fp32 K,V -> bf16 PER-FRAGMENT-CONTIGUOUS tiles ----------------
// K tile (pre-scaled by QK_SCALE): fragment f = t*2+c contiguous 1KB;
//   lane l=(g,a): K[kv0+16t+a][32c+8g..+8] * QK_SCALE
// V tile: fragment f = dt*2+c contiguous 1KB; lane l=(g,a): elem e =
//         V[kv0 + 32c+16(e>>2)+4g+(e&3)][16dt+a]
// XCD-swizzled grid so each head's tiles land in the L2 of the XCD that consumes them.
__global__ __launch_bounds__(256)
void prep_kernel(const float* __restrict__ K, const float* __restrict__ V,
                 __bf16* __restrict__ ws)
{
    __shared__ __bf16 v_s[64][72];
    const int tid  = threadIdx.x;
    const int bx   = blockIdx.x;                 // 0..1023
    const int orig = (bx & 7) * 128 + (bx >> 3); // XCD x owns orig in [x*128, x*128+128)
    const int h    = orig >> 6;
    const int tile = orig & 63;                  // seq*16 + it
    const int kv0  = tile * 64;
    __bf16* kb = ws + (size_t)h * HSTRIDE + (size_t)tile * TILE_E;
    __bf16* vt = ws + VT_OFF + (size_t)h * HSTRIDE + (size_t)tile * TILE_E;

    #pragma unroll
    for (int i = 0; i < 2; ++i) {
        const int c2 = tid + 256 * i;      // chunk id 0..511
        const int f  = c2 >> 6;
        const int l  = c2 & 63;
        const int g  = l >> 4, aa = l & 15;
        const int t  = f >> 1, cc = f & 1;
        const int r  = 16 * t + aa;
        const int d0 = 32 * cc + 8 * g;

        const float* kp = K + (size_t)(kv0 + r) * HD + h * HEAD_DIM + d0;
        float4 f0 = *(const float4*)kp, f1 = *(const float4*)(kp + 4);
        bf16x8 u = {(__bf16)(f0.x * QK_SCALE), (__bf16)(f0.y * QK_SCALE),
                    (__bf16)(f0.z * QK_SCALE), (__bf16)(f0.w * QK_SCALE),
                    (__bf16)(f1.x * QK_SCALE), (__bf16)(f1.y * QK_SCALE),
                    (__bf16)(f1.z * QK_SCALE), (__bf16)(f1.w * QK_SCALE)};
        *reinterpret_cast<bf16x8*>(kb + f * 512 + l * 8) = u;

        const float* vp = V + (size_t)(kv0 + r) * HD + h * HEAD_DIM + d0;
        float4 g0 = *(const float4*)vp, g1 = *(const float4*)(vp + 4);
        bf16x8 w = {(__bf16)g0.x, (__bf16)g0.y, (__bf16)g0.z, (__bf16)g0.w,
                    (__bf16)g1.x, (__bf16)g1.y, (__bf16)g1.z, (__bf16)g1.w};
        *reinterpret_cast<bf16x8*>(&v_s[r][d0]) = w;
    }
    __syncthreads();
    #pragma unroll
    for (int i = 0; i < 2; ++i) {
        const int c2 = tid + 256 * i;
        const int f  = c2 >> 6;
        const int l  = c2 & 63;
        const int g  = l >> 4, aa = l & 15;
        const int dt = f >> 1, cc = f & 1;
        const int d  = 16 * dt + aa;
        bf16x8 w;
        #pragma unroll
        for (int e = 0; e < 8; ++e) {
            const int kvl = 32 * cc + ((e >> 2) << 4) + 4 * g + (e & 3);
            w[e] = v_s[kvl][d];
        }
        *reinterpret_cast<bf16x8*>(vt + f * 512 + l * 8) = w;
    }
}

// --- attention: QR=16/wave (3 waves/SIMD), 3-buffer counted-vmcnt pipeline, raw barriers ---
__global__ __launch_bounds__(256, 4)
void fattn9_kernel(const float* __restrict__ Q, const __bf16* __restrict__ ws,
                   float* __restrict__ O)
{
    __shared__ __bf16 buf[3][2 * TILE_E];   // 3 x 16 KB: [K frags | V frags]

    const int tid  = threadIdx.x;
    const int lane = tid & 63;
    const int wave = tid >> 6;
    const int g    = lane >> 4;
    const int a    = lane & 15;

    // 1024 blocks (64 q rows each); bijective XCD chunking: XCD x gets orig in
    // [x*128, x*128+128) = heads [2x, 2x+2), matching prep's placement.
    const int b     = blockIdx.x;
    const int orig  = (b & 7) * 128 + (b >> 3);
    const int group = orig >> 4;          // h*4 + seq
    const int qt    = orig & 15;          // q-block within sequence
    const int h     = group >> 2;
    const int seq   = group & 3;
    const int q0    = seq * SEQL + qt * 64;   // block: 64 q rows; wave: 16

    const __bf16* kb_base = ws + (size_t)h * HSTRIDE + (size_t)seq * NTILE * TILE_E;
    const __bf16* vt_base = ws + VT_OFF + (size_t)h * HSTRIDE + (size_t)seq * NTILE * TILE_E;

    // Q fragments: lane holds Q row (q0 + wave*16 + a), d = 8g + 32c + [0..8)
    // (scale already folded into K by prep)
    bf16x8 qf[2];
    {
        const float* qp = Q + (size_t)(q0 + wave * 16 + a) * HD + h * HEAD_DIM + g * 8;
        #pragma unroll
        for (int c = 0; c < 2; ++c) {
            float4 f0 = *reinterpret_cast<const float4*>(qp + 32 * c);
            float4 f1 = *reinterpret_cast<const float4*>(qp + 32 * c + 4);
            qf[c][0] = (__bf16)f0.x; qf[c][1] = (__bf16)f0.y;
            qf[c][2] = (__bf16)f0.z; qf[c][3] = (__bf16)f0.w;
            qf[c][4] = (__bf16)f1.x; qf[c][5] = (__bf16)f1.y;
            qf[c][6] = (__bf16)f1.z; qf[c][7] = (__bf16)f1.w;
        }
    }

    f32x4 o_acc[4];
    #pragma unroll
    for (int dt = 0; dt < 4; ++dt) o_acc[dt] = (f32x4){0.f, 0.f, 0.f, 0.f};
    f32x4 l_acc = (f32x4){0.f, 0.f, 0.f, 0.f};

    bf16x8 ones;
    #pragma unroll
    for (int e = 0; e < 8; ++e) ones[e] = (__bf16)1.0f;

    const f32x4 minit = (f32x4){-FIXED_M, -FIXED_M, -FIXED_M, -FIXED_M};
    const int lb    = lane * 16;   // byte slot within a 1KB fragment
    const int stid8 = tid * 8;

    // 4 gload_lds insts per wave per stage (vmcnt += 4)
    auto stage = [&](const int bi, int t) {
        const __bf16* ks = kb_base + (size_t)t * TILE_E + stid8;
        const __bf16* vs = vt_base + (size_t)t * TILE_E + stid8;
        GLOAD_LDS16(ks,        &buf[bi][stid8]);
        GLOAD_LDS16(ks + 2048, &buf[bi][2048 + stid8]);
        GLOAD_LDS16(vs,        &buf[bi][TILE_E + stid8]);
        GLOAD_LDS16(vs + 2048, &buf[bi][TILE_E + 2048 + stid8]);
    };

    stage(0, 0);
    stage(1, 1);   // 8 outstanding

    #pragma unroll
    for (int t = 0; t < NTILE; ++t) {
        // wait own tile-t loads (leave t+1 in flight), barrier => everyone's t data ready
        asm volatile("s_waitcnt vmcnt(4)" ::: "memory");
        __builtin_amdgcn_sched_barrier(0);
        __builtin_amdgcn_s_barrier();
        __builtin_amdgcn_sched_barrier(0);

        // prefetch t+2 into the buffer freed by this barrier (tail re-stages tiles 0/1:
        // keeps per-wave vmcnt arithmetic uniform; harmless redundant loads)
        stage((t + 2) % 3, (t + 2) & (NTILE - 1));

        const char* kc = (const char*)&buf[t % 3][0];
        const char* vc = (const char*)&buf[t % 3][TILE_E];

        // ---- QK^T (swapped): s[q4][r] = S^T[kv=16q4+4g+r][q=a] - FIXED_M ----
        f32x4 s[4];
        __builtin_amdgcn_s_setprio(1);
        #pragma unroll
        for (int q4 = 0; q4 < 4; ++q4) {
            bf16x8 kf0 = *reinterpret_cast<const bf16x8*>(kc + (2 * q4) * 1024 + lb);
            bf16x8 kf1 = *reinterpret_cast<const bf16x8*>(kc + (2 * q4 + 1) * 1024 + lb);
            s[q4] = MFMA16(kf0, qf[0], minit);
            s[q4] = MFMA16(kf1, qf[1], s[q4]);
        }
        __builtin_amdgcn_s_setprio(0);

        // ---- fixed-shift softmax: p = exp2(s), raw v_exp_f32 ----
        // pf[c] elem bb -> kv = 32c + 16(bb>>2) + 4g + (bb&3)
        bf16x8 pf[2];
        #pragma unroll
        for (int c = 0; c < 2; ++c)
            #pragma unroll
            for (int bb = 0; bb < 8; ++bb)
                pf[c][bb] = (__bf16)__builtin_amdgcn_exp2f(s[2 * c + (bb >> 2)][bb & 3]);

        // ---- l row-sum + PV, all on the MFMA pipe ----
        __builtin_amdgcn_s_setprio(1);
        l_acc = MFMA16(pf[0], ones, l_acc);
        l_acc = MFMA16(pf[1], ones, l_acc);
        #pragma unroll
        for (int dt = 0; dt < 4; ++dt) {
            bf16x8 vf0 = *reinterpret_cast<const bf16x8*>(vc + (2 * dt) * 1024 + lb);
            bf16x8 vf1 = *reinterpret_cast<const bf16x8*>(vc + (2 * dt + 1) * 1024 + lb);
            o_acc[dt] = MFMA16(pf[0], vf0, o_acc[dt]);
            o_acc[dt] = MFMA16(pf[1], vf1, o_acc[dt]);
        }
        __builtin_amdgcn_s_setprio(0);
        // no trailing barrier: next iteration's waitcnt+barrier provides the sync
    }

    // ---- epilogue: O rows q = wave*16 + 4g + r, cols d = 16dt + a ----
    #pragma unroll
    for (int r = 0; r < 4; ++r) {
        const float inv = 1.0f / l_acc[r];
        float* op = O + (size_t)(q0 + wave * 16 + 4 * g + r) * HD + h * HEAD_DIM + a;
        #pragma unroll
        for (int dt = 0; dt < 4; ++dt)
            op[16 * dt] = o_acc[dt][r] * inv;
    }
}

extern "C" void kernel_launch(void* const* d_in, const int* in_sizes, int n_in,
                              void* d_out, int out_size, void* d_ws, size_t ws_size,
                              hipStream_t stream) {
    const float* q = (const float*)d_in[0];
    const float* k = (const float*)d_in[1];
    const float* v = (const float*)d_in[2];
    float* out = (float*)d_out;
    __bf16* ws = (__bf16*)d_ws;   // 16 MB: 8 MB K-fragments (pre-scaled) + 8 MB V-fragments

    prep_kernel<<<1024, 256, 0, stream>>>(k, v, ws);
    fattn9_kernel<<<1024, 256, 0, stream>>>(q, ws, out);
}

// Round 10
// 36.167 us; speedup vs baseline: 1.0810x; 1.0810x over previous
//
#include <hip/hip_runtime.h>
#include <hip/hip_bf16.h>

#define NUM_HEADS 16
#define HEAD_DIM  64
#define HD        1024   // NUM_HEADS*HEAD_DIM
#define SEQL      1024
#define NTILE     16     // kv tiles per sequence
#define TILE_E    4096   // elements per 64x64 bf16 tile (8 KB)
#define HSTRIDE   (64 * TILE_E)          // 64 tiles per head
#define VT_OFF    (NUM_HEADS * HSTRIDE)  // V-fragment array offset in ws (elems)
#define FIXED_M   12.0f                  // fixed log2-domain shift (max score ~8 sigma)
#define QK_SCALE  0.1803368801111204f    // 0.125 * log2(e), folded into K during prep

typedef __bf16 bf16x8 __attribute__((ext_vector_type(8)));
typedef float  f32x4  __attribute__((ext_vector_type(4)));

#define MFMA16(A, B, C) __builtin_amdgcn_mfma_f32_16x16x32_bf16((A), (B), (C), 0, 0, 0)
#define GLOAD_LDS16(gp, lp) \
  __builtin_amdgcn_global_load_lds((const __attribute__((address_space(1))) void*)(gp), \
                                   (__attribute__((address_space(3))) void*)(lp), 16, 0, 0)

// ---------------- prep: fp32 K,V -> bf16 PER-FRAGMENT-CONTIGUOUS tiles ----------------
// K tile (pre-scaled by QK_SCALE): fragment f = t*2+c contiguous 1KB;
//   lane l=(g,a): K[kv0+16t+a][32c+8g..+8] * QK_SCALE
// V tile: fragment f = dt*2+c contiguous 1KB; lane l=(g,a): elem e =
//         V[kv0 + 32c+16(e>>2)+4g+(e&3)][16dt+a]
// XCD-swizzled grid so each head's tiles land in the L2 of the XCD that consumes them.
__global__ __launch_bounds__(256)
void prep_kernel(const float* __restrict__ K, const float* __restrict__ V,
                 __bf16* __restrict__ ws)
{
    __shared__ __bf16 v_s[64][72];
    const int tid  = threadIdx.x;
    const int bx   = blockIdx.x;                 // 0..1023
    const int orig = (bx & 7) * 128 + (bx >> 3); // XCD x owns orig in [x*128, x*128+128)
    const int h    = orig >> 6;
    const int tile = orig & 63;                  // seq*16 + it
    const int kv0  = tile * 64;
    __bf16* kb = ws + (size_t)h * HSTRIDE + (size_t)tile * TILE_E;
    __bf16* vt = ws + VT_OFF + (size_t)h * HSTRIDE + (size_t)tile * TILE_E;

    #pragma unroll
    for (int i = 0; i < 2; ++i) {
        const int c2 = tid + 256 * i;      // chunk id 0..511
        const int f  = c2 >> 6;
        const int l  = c2 & 63;
        const int g  = l >> 4, aa = l & 15;
        const int t  = f >> 1, cc = f & 1;
        const int r  = 16 * t + aa;
        const int d0 = 32 * cc + 8 * g;

        const float* kp = K + (size_t)(kv0 + r) * HD + h * HEAD_DIM + d0;
        float4 f0 = *(const float4*)kp, f1 = *(const float4*)(kp + 4);
        bf16x8 u = {(__bf16)(f0.x * QK_SCALE), (__bf16)(f0.y * QK_SCALE),
                    (__bf16)(f0.z * QK_SCALE), (__bf16)(f0.w * QK_SCALE),
                    (__bf16)(f1.x * QK_SCALE), (__bf16)(f1.y * QK_SCALE),
                    (__bf16)(f1.z * QK_SCALE), (__bf16)(f1.w * QK_SCALE)};
        *reinterpret_cast<bf16x8*>(kb + f * 512 + l * 8) = u;

        const float* vp = V + (size_t)(kv0 + r) * HD + h * HEAD_DIM + d0;
        float4 g0 = *(const float4*)vp, g1 = *(const float4*)(vp + 4);
        bf16x8 w = {(__bf16)g0.x, (__bf16)g0.y, (__bf16)g0.z, (__bf16)g0.w,
                    (__bf16)g1.x, (__bf16)g1.y, (__bf16)g1.z, (__bf16)g1.w};
        *reinterpret_cast<bf16x8*>(&v_s[r][d0]) = w;
    }
    __syncthreads();
    #pragma unroll
    for (int i = 0; i < 2; ++i) {
        const int c2 = tid + 256 * i;
        const int f  = c2 >> 6;
        const int l  = c2 & 63;
        const int g  = l >> 4, aa = l & 15;
        const int dt = f >> 1, cc = f & 1;
        const int d  = 16 * dt + aa;
        bf16x8 w;
        #pragma unroll
        for (int e = 0; e < 8; ++e) {
            const int kvl = 32 * cc + ((e >> 2) << 4) + 4 * g + (e & 3);
            w[e] = v_s[kvl][d];
        }
        *reinterpret_cast<bf16x8*>(vt + f * 512 + l * 8) = w;
    }
}

// --- attention: QR=32/wave, 4-buffer depth-3 counted-vmcnt pipeline, raw barriers ---
__global__ __launch_bounds__(256, 4)
void fattn10_kernel(const float* __restrict__ Q, const __bf16* __restrict__ ws,
                    float* __restrict__ O)
{
    __shared__ __bf16 buf[4][2 * TILE_E];   // 4 x 16 KB: [K frags | V frags]

    const int tid  = threadIdx.x;
    const int lane = tid & 63;
    const int wave = tid >> 6;
    const int g    = lane >> 4;
    const int a    = lane & 15;

    // 512 blocks; bijective XCD chunking: XCD x gets orig in [x*64, x*64+64)
    const int b     = blockIdx.x;
    const int orig  = (b & 7) * 64 + (b >> 3);
    const int group = orig >> 3;          // h*4 + seq
    const int qb    = orig & 7;
    const int h     = group >> 2;
    const int seq   = group & 3;
    const int q0    = seq * SEQL + qb * 128;   // block: 128 q rows; wave: 32

    const __bf16* kb_base = ws + (size_t)h * HSTRIDE + (size_t)seq * NTILE * TILE_E;
    const __bf16* vt_base = ws + VT_OFF + (size_t)h * HSTRIDE + (size_t)seq * NTILE * TILE_E;

    // Q fragments for 2 q-subtiles (scale folded into K by prep)
    bf16x8 qf[2][2];
    #pragma unroll
    for (int u = 0; u < 2; ++u) {
        const float* qp = Q + (size_t)(q0 + wave * 32 + u * 16 + a) * HD + h * HEAD_DIM + g * 8;
        #pragma unroll
        for (int c = 0; c < 2; ++c) {
            float4 f0 = *reinterpret_cast<const float4*>(qp + 32 * c);
            float4 f1 = *reinterpret_cast<const float4*>(qp + 32 * c + 4);
            qf[u][c][0] = (__bf16)f0.x; qf[u][c][1] = (__bf16)f0.y;
            qf[u][c][2] = (__bf16)f0.z; qf[u][c][3] = (__bf16)f0.w;
            qf[u][c][4] = (__bf16)f1.x; qf[u][c][5] = (__bf16)f1.y;
            qf[u][c][6] = (__bf16)f1.z; qf[u][c][7] = (__bf16)f1.w;
        }
    }

    f32x4 o_acc[2][4];
    #pragma unroll
    for (int u = 0; u < 2; ++u)
        #pragma unroll
        for (int dt = 0; dt < 4; ++dt) o_acc[u][dt] = (f32x4){0.f, 0.f, 0.f, 0.f};
    f32x4 l_acc[2] = {(f32x4){0.f, 0.f, 0.f, 0.f}, (f32x4){0.f, 0.f, 0.f, 0.f}};

    bf16x8 ones;
    #pragma unroll
    for (int e = 0; e < 8; ++e) ones[e] = (__bf16)1.0f;

    const f32x4 minit = (f32x4){-FIXED_M, -FIXED_M, -FIXED_M, -FIXED_M};
    const int lb    = lane * 16;   // byte slot within a 1KB fragment
    const int stid8 = tid * 8;

    // 4 gload_lds insts per wave per stage (vmcnt += 4)
    auto stage = [&](const int bi, int t) {
        const __bf16* ks = kb_base + (size_t)t * TILE_E + stid8;
        const __bf16* vs = vt_base + (size_t)t * TILE_E + stid8;
        GLOAD_LDS16(ks,        &buf[bi][stid8]);
        GLOAD_LDS16(ks + 2048, &buf[bi][2048 + stid8]);
        GLOAD_LDS16(vs,        &buf[bi][TILE_E + stid8]);
        GLOAD_LDS16(vs + 2048, &buf[bi][TILE_E + 2048 + stid8]);
    };

    stage(0, 0);
    stage(1, 1);
    stage(2, 2);   // 12 outstanding, prefetch distance 3

    #pragma unroll
    for (int t = 0; t < NTILE; ++t) {
        // wait own tile-t loads (leave t+1,t+2 in flight), barrier => all waves' t data ready
        asm volatile("s_waitcnt vmcnt(8)" ::: "memory");
        __builtin_amdgcn_sched_barrier(0);
        __builtin_amdgcn_s_barrier();
        __builtin_amdgcn_sched_barrier(0);

        // prefetch t+3 into the buffer freed by this barrier (tail wraps: keeps per-wave
        // vmcnt arithmetic uniform; harmless redundant loads)
        stage((t + 3) & 3, (t + 3) & (NTILE - 1));

        const char* kc = (const char*)&buf[t & 3][0];
        const char* vc = (const char*)&buf[t & 3][TILE_E];

        // ---- QK^T (swapped): s[u][q4][r] = S^T[kv=16q4+4g+r][q=a] - FIXED_M ----
        f32x4 s[2][4];
        __builtin_amdgcn_s_setprio(1);
        #pragma unroll
        for (int q4 = 0; q4 < 4; ++q4) {
            bf16x8 kf0 = *reinterpret_cast<const bf16x8*>(kc + (2 * q4) * 1024 + lb);
            bf16x8 kf1 = *reinterpret_cast<const bf16x8*>(kc + (2 * q4 + 1) * 1024 + lb);
            s[0][q4] = MFMA16(kf0, qf[0][0], minit);
            s[0][q4] = MFMA16(kf1, qf[0][1], s[0][q4]);
            s[1][q4] = MFMA16(kf0, qf[1][0], minit);
            s[1][q4] = MFMA16(kf1, qf[1][1], s[1][q4]);
        }
        __builtin_amdgcn_s_setprio(0);

        // ---- fixed-shift softmax: p = exp2(s), raw v_exp_f32 ----
        // pf[u][c] elem bb -> kv = 32c + 16(bb>>2) + 4g + (bb&3)
        bf16x8 pf[2][2];
        #pragma unroll
        for (int u = 0; u < 2; ++u)
            #pragma unroll
            for (int c = 0; c < 2; ++c)
                #pragma unroll
                for (int bb = 0; bb < 8; ++bb)
                    pf[u][c][bb] = (__bf16)__builtin_amdgcn_exp2f(s[u][2 * c + (bb >> 2)][bb & 3]);

        // ---- l row-sum + PV (V fragments shared across q-subtiles) ----
        __builtin_amdgcn_s_setprio(1);
        #pragma unroll
        for (int u = 0; u < 2; ++u) {
            l_acc[u] = MFMA16(pf[u][0], ones, l_acc[u]);
            l_acc[u] = MFMA16(pf[u][1], ones, l_acc[u]);
        }
        #pragma unroll
        for (int dt = 0; dt < 4; ++dt) {
            bf16x8 vf0 = *reinterpret_cast<const bf16x8*>(vc + (2 * dt) * 1024 + lb);
            bf16x8 vf1 = *reinterpret_cast<const bf16x8*>(vc + (2 * dt + 1) * 1024 + lb);
            #pragma unroll
            for (int u = 0; u < 2; ++u) {
                o_acc[u][dt] = MFMA16(pf[u][0], vf0, o_acc[u][dt]);
                o_acc[u][dt] = MFMA16(pf[u][1], vf1, o_acc[u][dt]);
            }
        }
        __builtin_amdgcn_s_setprio(0);
        // no trailing barrier: next iteration's waitcnt+barrier provides the sync
    }

    // ---- epilogue: O rows q = wave*32 + u*16 + 4g + r, cols d = 16dt + a ----
    #pragma unroll
    for (int u = 0; u < 2; ++u)
        #pragma unroll
        for (int r = 0; r < 4; ++r) {
            const float inv = 1.0f / l_acc[u][r];
            float* op = O + (size_t)(q0 + wave * 32 + u * 16 + 4 * g + r) * HD + h * HEAD_DIM + a;
            #pragma unroll
            for (int dt = 0; dt < 4; ++dt)
                op[16 * dt] = o_acc[u][dt][r] * inv;
        }
}

extern "C" void kernel_launch(void* const* d_in, const int* in_sizes, int n_in,
                              void* d_out, int out_size, void* d_ws, size_t ws_size,
                              hipStream_t stream) {
    const float* q = (const float*)d_in[0];
    const float* k = (const float*)d_in[1];
    const float* v = (const float*)d_in[2];
    float* out = (float*)d_out;
    __bf16* ws = (__bf16*)d_ws;   // 16 MB: 8 MB K-fragments (pre-scaled) + 8 MB V-fragments

    prep_kernel<<<1024, 256, 0, stream>>>(k, v, ws);
    fattn10_kernel<<<512, 256, 0, stream>>>(q, ws, out);
}